// Round 7
// baseline (55.153 us; speedup 1.0000x reference)
//
#include <hip/hip_runtime.h>

// Problem: B=16, S=256, IN=128, OUT=128, HID=512
// Restructured: y[b,o] = sum_{k=h*128+i} M[b,k]*W2flat[k*128+o] + sum_i sx[b,i]*b2[i*128+o]
//   where M[b,h,i] = sum_s h[b,s,h]*x[b,s,i],  h = relu(x@W1+b1)
// then out = y @ Wfc + bfc.
//
// 4-kernel chain: A (h), B (M + fused sx), C (256-way split-K partials), D (final).

// ws layout (floats):
//   h:    [4096][512]        off 0        size 2097152
//   M:    [16][65536]        off 2097152  size 1048576
//   part: [256][16][128]     off 3145728  size 524288
//   sx:   [16][128]          off 3670016  size 2048

// ---------- Stage A: h = relu(x @ W1 + b1)  (4096x128 @ 128x512) ----------
__global__ __launch_bounds__(256) void k_hyp1(const float* __restrict__ x,
        const float* __restrict__ W1, const float* __restrict__ b1,
        float* __restrict__ h) {
    __shared__ float AsT[128][68];  // x tile TRANSPOSED: k x 64 tokens (+4 pad)
    __shared__ float Bs[128][68];   // W1 tile: 128 k x 64 hid (+4 pad)
    const int tid = threadIdx.x;
    const int t0 = (blockIdx.x >> 3) * 64;
    const int h0 = (blockIdx.x & 7) * 64;
    {
        // x load: lane tl owns token row, cg picks float4 chunk; store transposed
        const int tl = tid & 63, cg = tid >> 6;
        #pragma unroll
        for (int p = 0; p < 8; ++p) {
            const int c4 = (cg * 8 + p) * 4;
            const float4 v = *(const float4*)&x[(size_t)(t0 + tl) * 128 + c4];
            AsT[c4 + 0][tl] = v.x;
            AsT[c4 + 1][tl] = v.y;
            AsT[c4 + 2][tl] = v.z;
            AsT[c4 + 3][tl] = v.w;
        }
    }
    {
        const int r = tid >> 4, c4 = (tid & 15) * 4;
        #pragma unroll
        for (int p = 0; p < 8; ++p) {
            const int kk = p * 16 + r;
            *(float4*)&Bs[kk][c4] = *(const float4*)&W1[kk * 512 + h0 + c4];
        }
    }
    __syncthreads();
    const int ty = tid >> 4, tx = tid & 15;
    float acc[4][4] = {};
    #pragma unroll 8
    for (int k = 0; k < 128; ++k) {
        const float4 a = *(const float4*)&AsT[k][ty * 4];
        const float4 b = *(const float4*)&Bs[k][tx * 4];
        const float av[4] = {a.x, a.y, a.z, a.w};
        const float bv[4] = {b.x, b.y, b.z, b.w};
        #pragma unroll
        for (int i = 0; i < 4; ++i)
            #pragma unroll
            for (int j = 0; j < 4; ++j)
                acc[i][j] += av[i] * bv[j];
    }
    #pragma unroll
    for (int i = 0; i < 4; ++i) {
        float4 v; float* vp = (float*)&v;
        #pragma unroll
        for (int j = 0; j < 4; ++j) {
            float t = acc[i][j] + b1[h0 + tx * 4 + j];
            vp[j] = t > 0.f ? t : 0.f;
        }
        *(float4*)&h[(size_t)(t0 + ty * 4 + i) * 512 + h0 + tx * 4] = v;
    }
}

// ---------- Stage B: M[b,h,i] = sum_s h[b,s,h]*x[b,s,i]; fused sx[b,i]=sum_s x[b,s,i] ----------
__global__ __launch_bounds__(256) void k_hyp2(const float* __restrict__ x,
        const float* __restrict__ h, float* __restrict__ M,
        float* __restrict__ sx) {
    __shared__ float hs[64][68];
    __shared__ float xs[64][68];
    const int tid = threadIdx.x;
    const int b  = blockIdx.x >> 4;
    const int h0 = ((blockIdx.x >> 1) & 7) * 64;
    const int i0 = (blockIdx.x & 1) * 64;
    const int ty = tid >> 4, tx = tid & 15;
    float acc[4][4] = {};
    float sxacc = 0.f;
    for (int s0 = 0; s0 < 256; s0 += 64) {
        __syncthreads();
        {
            const int r = tid >> 4, c4 = (tid & 15) * 4;
            #pragma unroll
            for (int p = 0; p < 4; ++p) {
                const int sl = p * 16 + r;
                *(float4*)&hs[sl][c4] = *(const float4*)&h[(size_t)(b * 256 + s0 + sl) * 512 + h0 + c4];
                *(float4*)&xs[sl][c4] = *(const float4*)&x[(size_t)(b * 256 + s0 + sl) * 128 + i0 + c4];
            }
        }
        __syncthreads();
        if (h0 == 0 && tid < 64) {
            #pragma unroll 16
            for (int sl = 0; sl < 64; ++sl)
                sxacc += xs[sl][tid];
        }
        #pragma unroll 8
        for (int k = 0; k < 64; ++k) {
            const float4 a = *(const float4*)&hs[k][ty * 4];
            const float4 c = *(const float4*)&xs[k][tx * 4];
            const float av[4] = {a.x, a.y, a.z, a.w};
            const float cv[4] = {c.x, c.y, c.z, c.w};
            #pragma unroll
            for (int i = 0; i < 4; ++i)
                #pragma unroll
                for (int j = 0; j < 4; ++j)
                    acc[i][j] += av[i] * cv[j];
        }
    }
    if (h0 == 0 && tid < 64)
        sx[b * 128 + i0 + tid] = sxacc;
    #pragma unroll
    for (int i = 0; i < 4; ++i) {
        float4 v; float* vp = (float*)&v;
        #pragma unroll
        for (int j = 0; j < 4; ++j) vp[j] = acc[i][j];
        *(float4*)&M[(size_t)b * 65536 + (h0 + ty * 4 + i) * 128 + i0 + tx * 4] = v;
    }
}

// ---------- Stage C: split-K partials of y = M @ W2flat (K=256 per block) ----------
__global__ __launch_bounds__(256) void k_hyp3(const float* __restrict__ M,
        const float* __restrict__ W2, float* __restrict__ part) {
    __shared__ float Ms[16][256];
    const int tid = threadIdx.x;
    const int p = blockIdx.x;
    const int k0 = p * 256;
    #pragma unroll
    for (int r = 0; r < 4; ++r) {
        const int idx = r * 256 + tid;          // float4 index over [16][64]
        const int b = idx >> 6, kk4 = idx & 63;
        *(float4*)&Ms[b][kk4 * 4] = *(const float4*)&M[(size_t)b * 65536 + k0 + kk4 * 4];
    }
    __syncthreads();
    const int o = tid & 127, half = tid >> 7;
    float acc[8] = {};
    #pragma unroll 2
    for (int kk4 = 0; kk4 < 64; ++kk4) {
        const float w0 = W2[(size_t)(k0 + kk4 * 4 + 0) * 128 + o];
        const float w1 = W2[(size_t)(k0 + kk4 * 4 + 1) * 128 + o];
        const float w2 = W2[(size_t)(k0 + kk4 * 4 + 2) * 128 + o];
        const float w3 = W2[(size_t)(k0 + kk4 * 4 + 3) * 128 + o];
        #pragma unroll
        for (int j = 0; j < 8; ++j) {
            const float4 m = *(const float4*)&Ms[half * 8 + j][kk4 * 4];
            acc[j] += m.x * w0 + m.y * w1 + m.z * w2 + m.w * w3;
        }
    }
    #pragma unroll
    for (int j = 0; j < 8; ++j)
        part[(size_t)(p * 16 + half * 8 + j) * 128 + o] = acc[j];
}

// ---------- Stage D: reduce 256 partials + b2 term + Wfc + bfc ----------
__global__ __launch_bounds__(512) void k_hyp4(const float* __restrict__ part,
        const float* __restrict__ sx, const float* __restrict__ b2,
        const float* __restrict__ Wfc, const float* __restrict__ bfc,
        float* __restrict__ out) {
    __shared__ float sh[4][128];
    __shared__ float sxs[128];
    __shared__ float ysh[128];
    const int b = blockIdx.x;
    const int t = threadIdx.x & 127;
    const int g = threadIdx.x >> 7;     // 4 groups, each 1/4 of serial work
    float y = 0.f;
    #pragma unroll 8
    for (int pp = g * 64; pp < g * 64 + 64; ++pp)
        y += part[(size_t)(pp * 16 + b) * 128 + t];
    if (g == 0) sxs[t] = sx[b * 128 + t];
    __syncthreads();
    #pragma unroll 8
    for (int i = g * 32; i < g * 32 + 32; ++i)
        y += sxs[i] * b2[i * 128 + t];
    sh[g][t] = y;
    __syncthreads();
    if (g == 0) ysh[t] = sh[0][t] + sh[1][t] + sh[2][t] + sh[3][t];
    __syncthreads();
    float o = 0.f;
    #pragma unroll 8
    for (int oo = g * 32; oo < g * 32 + 32; ++oo)
        o += ysh[oo] * Wfc[oo * 128 + t];
    sh[g][t] = o;
    __syncthreads();
    if (g == 0)
        out[b * 128 + t] = bfc[t] + sh[0][t] + sh[1][t] + sh[2][t] + sh[3][t];
}

extern "C" void kernel_launch(void* const* d_in, const int* in_sizes, int n_in,
                              void* d_out, int out_size, void* d_ws, size_t ws_size,
                              hipStream_t stream) {
    const float* x   = (const float*)d_in[0];
    const float* W1  = (const float*)d_in[1];
    const float* b1  = (const float*)d_in[2];
    const float* W2  = (const float*)d_in[3];
    const float* b2  = (const float*)d_in[4];
    const float* Wfc = (const float*)d_in[5];
    const float* bfc = (const float*)d_in[6];
    float* ws   = (float*)d_ws;
    float* h    = ws;
    float* M    = ws + 2097152;
    float* part = ws + 3145728;
    float* sx   = ws + 3670016;
    float* out  = (float*)d_out;

    k_hyp1<<<512, 256, 0, stream>>>(x, W1, b1, h);
    k_hyp2<<<256, 256, 0, stream>>>(x, h, M, sx);
    k_hyp3<<<256, 256, 0, stream>>>(M, W2, part);
    k_hyp4<<<16,  512, 0, stream>>>(part, sx, b2, Wfc, bfc, out);
}